// Round 6
// baseline (183.726 us; speedup 1.0000x reference)
//
#include <hip/hip_runtime.h>
#include <stdint.h>

#define BATCH 16
#define CIN   64
#define COUT  64
#define NBR   8
#define HH    128
#define WW    128
#define XBH   130              // padded height
#define XBW   130              // padded width
#define PSTR  68               // ushorts per pixel in xb AND in LDS (64 ch + 4 pad)
#define NTILES 1024

typedef __attribute__((ext_vector_type(8)))  short short8;
typedef __attribute__((ext_vector_type(16))) float f32x16;

// round-half-up f32->bf16 (inputs are tame normals; 3.4x error headroom measured)
__device__ __forceinline__ unsigned int f2bf_hi(float f) {
    union { float f; uint32_t u; } v; v.f = f;
    return (v.u + 0x8000u) >> 16;
}
// RNE version
__device__ __forceinline__ unsigned short f2bf(float f) {
    union { float f; uint32_t u; } v; v.f = f;
    uint32_t u = v.u;
    return (unsigned short)((u + 0x7FFFu + ((u >> 16) & 1u)) >> 16);
}
__device__ __forceinline__ short8 gld_frag(const unsigned short* p) {
    union { uint4 u; short8 s; } t;
    t.u = *(const uint4*)p;            // 16B aligned
    return t.s;
}
__device__ __forceinline__ short8 lds_frag(const unsigned short* p) {
    union { uint2 u[2]; short8 s; } t;
    t.u[0] = *(const uint2*)p;         // 8B aligned
    t.u[1] = *(const uint2*)(p + 4);
    return t.s;
}
// async global->LDS, 16B per lane; LDS dest is wave-uniform base + lane*16
__device__ __forceinline__ void gload_lds16(const unsigned short* g, unsigned short* l) {
    __builtin_amdgcn_global_load_lds(
        (const __attribute__((address_space(1))) unsigned int*)g,
        (__attribute__((address_space(3))) unsigned int*)l, 16, 0, 0);
}

// -------- kernel 1: fused {softmax+filter combine (blocks<1024)} | {x->xb cast} --------
// xb[b][h'][w'][68] bf16, 136 B/pixel; rows 0/129 and cols 0/129 are zero halo.
__global__ __launch_bounds__(256)
void k_pc(const float* __restrict__ cond,
          const float* __restrict__ sel_w,
          const float* __restrict__ sel_b,
          const float* __restrict__ filt_w,
          const float* __restrict__ filt_b,
          const float* __restrict__ x,
          unsigned short* __restrict__ wfilt,
          float* __restrict__ cbias,
          unsigned short* __restrict__ xb) {
    __shared__ float4 lw4[NBR * 144];          // 18432 B (prep branch only)
    __shared__ float lg[NBR];
    const int tid = threadIdx.x;

    if (blockIdx.x < NTILES) {
        // ---------------- prep branch (unchanged, verified) ----------------
        float* lw = (float*)lw4;
        const int blk = blockIdx.x;
        const int b = blk >> 6, o = blk & 63;

        const float4* src4 = (const float4*)filt_w;
        #pragma unroll
        for (int i = tid; i < NBR * 144; i += 256)
            lw4[i] = src4[((i / 144) * COUT + o) * 144 + (i % 144)];

        {
            const int lane = tid & 63, w = tid >> 6;
            const float c0 = cond[b * CIN + lane];
            #pragma unroll
            for (int k = 0; k < 2; ++k) {
                const int n = w + k * 4;
                float p = c0 * sel_w[n * CIN + lane];
                #pragma unroll
                for (int off = 32; off > 0; off >>= 1)
                    p += __shfl_down(p, off, 64);
                if (lane == 0) lg[n] = p + sel_b[n];
            }
        }
        __syncthreads();

        float w8[NBR];
        {
            float m = -1e30f;
            #pragma unroll
            for (int n = 0; n < NBR; ++n) m = fmaxf(m, lg[n]);
            float s = 0.f;
            #pragma unroll
            for (int n = 0; n < NBR; ++n) { w8[n] = __expf(lg[n] - m); s += w8[n]; }
            const float inv = 1.f / s;
            #pragma unroll
            for (int n = 0; n < NBR; ++n) w8[n] *= inv;
        }

        #pragma unroll
        for (int idx = tid; idx < 576; idx += 256) {
            const int t = idx >> 6, c = idx & 63;
            float acc = 0.f;
            #pragma unroll
            for (int n = 0; n < NBR; ++n)
                acc += w8[n] * lw[n * 576 + c * 9 + t];
            wfilt[(((long)(b * 9 + t) * COUT + o) << 6) + c] = f2bf(acc);
        }
        if (tid == 0) {
            float ab = 0.f;
            #pragma unroll
            for (int n = 0; n < NBR; ++n) ab += w8[n] * filt_b[n * COUT + o];
            cbias[b * COUT + o] = ab;
        }
    } else {
        // ---------------- cast branch: one padded row of xb ----------------
        const int id = blockIdx.x - NTILES;        // 0 .. 16*130-1
        const int hp = id % XBH;
        const int b  = id / XBH;
        unsigned short* dst = xb + (long)(b * XBH + hp) * XBW * PSTR;
        const bool zrow = (hp == 0) || (hp == XBH - 1);
        const int h = hp - 1;
        const long cs = (long)HH * WW;

        for (int t = tid; t < XBW * 8; t += 256) {     // 130 pixels x 8 chunks of 8ch
            const int wp = t >> 3, q = t & 7;
            uint4 v; v.x = v.y = v.z = v.w = 0u;
            if (!zrow && wp != 0 && wp != XBW - 1) {
                const float* px = x + (((long)(b * CIN + q * 8)) * HH + h) * WW + (wp - 1);
                v.x = f2bf_hi(px[0])      | (f2bf_hi(px[cs])     << 16);
                v.y = f2bf_hi(px[2 * cs]) | (f2bf_hi(px[3 * cs]) << 16);
                v.z = f2bf_hi(px[4 * cs]) | (f2bf_hi(px[5 * cs]) << 16);
                v.w = f2bf_hi(px[6 * cs]) | (f2bf_hi(px[7 * cs]) << 16);
            }
            unsigned short* dp = dst + wp * PSTR + q * 8;    // 8B aligned (PSTR*2=136)
            uint2 u0, u1;
            u0.x = v.x; u0.y = v.y; u1.x = v.z; u1.y = v.w;
            *(uint2*)dp       = u0;
            *(uint2*)(dp + 4) = u1;
            if (q == 7) {                                    // zero the 8B pad
                uint2 z; z.x = z.y = 0u;
                *(uint2*)(dst + wp * PSTR + 64) = z;
            }
        }
    }
}

// -------- kernel 2: conv, RT=4 tiles -> 27.7KB LDS, 4 blocks/CU, 8 generations --------
#define RT 4
#define WT 32
#define SLABW 34                      // WT + 2 halo
#define SLABR 6                       // RT + 2 halo
#define ROWUS (SLABW * PSTR)          // 2312 ushorts = 4624 B per slab row (16B multiple)
#define NCHUNK (SLABR * ROWUS / 8)    // 1734 16B chunks per slab

__global__ __launch_bounds__(256, 4)
void k_conv(const unsigned short* __restrict__ xb,
            const unsigned short* __restrict__ wfilt,
            const float* __restrict__ cbias,
            float* __restrict__ out) {
    __shared__ unsigned short lx[SLABR * ROWUS];          // 27744 B

    const int b  = blockIdx.z;
    const int h0 = blockIdx.y * RT;
    const int w0 = blockIdx.x * WT;
    const int tid = threadIdx.x;

    // ---- stage slab: 6 contiguous 4624B row segments, fire-and-forget DMA ----
    const unsigned short* srcb = xb + ((long)(b * XBH + h0) * XBW + w0) * PSTR;
    #pragma unroll
    for (int k = 0; k < 7; ++k) {
        const int t = tid + k * 256;
        if (t < NCHUNK) {
            const int row = t / 289;              // 289 chunks per row (4624/16)
            const int rc  = t - row * 289;
            gload_lds16(srcb + (long)row * (XBW * PSTR) + rc * 8, lx + t * 8);
        }
    }

    const int lane = tid & 63;
    const int wave = tid >> 6;
    const int l31  = lane & 31;
    const int lh   = lane >> 5;
    const int wp   = wave & 1;        // row-pair index (output rows 2wp, 2wp+1)
    const int wc   = wave >> 1;       // channel half (out channels wc*32..wc*32+31)
    const int r0   = wp * 2;

    // A source for this wave's channel half
    const unsigned short* wf = wfilt + (long)b * 9 * COUT * CIN + wc * 32 * CIN;

    // prefetch tap-0 A fragments (overlaps the LDS DMA)
    short8 A[4];
    #pragma unroll
    for (int cc = 0; cc < 4; ++cc)
        A[cc] = gld_frag(wf + l31 * CIN + cc * 16 + lh * 8);

    // bias-initialized accumulators (C/D row m = (i&3)+8*(i>>2)+4*lh)
    f32x16 acc0, acc1;
    #pragma unroll
    for (int i = 0; i < 16; ++i) {
        const int m = (i & 3) + 8 * (i >> 2) + 4 * lh;
        const float bb = cbias[b * COUT + wc * 32 + m];
        acc0[i] = bb; acc1[i] = bb;
    }

    __syncthreads();   // vmcnt(0) drain: slab + A frags ready

    #pragma unroll
    for (int tap = 0; tap < 9; ++tap) {
        // prefetch next tap's A into fresh registers BEFORE this tap's MFMAs
        short8 nA[4];
        if (tap < 8) {
            const unsigned short* wn = wf + (long)(tap + 1) * COUT * CIN;
            #pragma unroll
            for (int cc = 0; cc < 4; ++cc)
                nA[cc] = gld_frag(wn + l31 * CIN + cc * 16 + lh * 8);
        }
        const int kh = tap / 3, kw = tap % 3;
        #pragma unroll
        for (int cc = 0; cc < 4; ++cc) {
            const int kofs = cc * 16 + lh * 8;
            short8 b0 = lds_frag(&lx[((r0     + kh) * SLABW + l31 + kw) * PSTR + kofs]);
            short8 b1 = lds_frag(&lx[((r0 + 1 + kh) * SLABW + l31 + kw) * PSTR + kofs]);
            acc0 = __builtin_amdgcn_mfma_f32_32x32x16_bf16(A[cc], b0, acc0, 0, 0, 0);
            acc1 = __builtin_amdgcn_mfma_f32_32x32x16_bf16(A[cc], b1, acc1, 0, 0, 0);
        }
        #pragma unroll
        for (int cc = 0; cc < 4; ++cc) A[cc] = nA[cc];
    }

    #pragma unroll
    for (int pb = 0; pb < 2; ++pb) {
        const f32x16 v = pb == 0 ? acc0 : acc1;
        const int hrow = h0 + r0 + pb;
        float* op = out + (((long)(b * COUT + wc * 32) * HH + hrow) * WW + w0 + l31);
        #pragma unroll
        for (int i = 0; i < 16; ++i) {
            const int m = (i & 3) + 8 * (i >> 2) + 4 * lh;
            op[(long)m * HH * WW] = v[i];
        }
    }
}

extern "C" void kernel_launch(void* const* d_in, const int* in_sizes, int n_in,
                              void* d_out, int out_size, void* d_ws, size_t ws_size,
                              hipStream_t stream) {
    const float* x      = (const float*)d_in[0];
    const float* cond   = (const float*)d_in[1];
    const float* filt_w = (const float*)d_in[2];
    const float* filt_b = (const float*)d_in[3];
    const float* sel_w  = (const float*)d_in[4];
    const float* sel_b  = (const float*)d_in[5];
    float* out = (float*)d_out;

    // ws: cbias [16][64] f32 @0; wfilt [16][9][64][64] bf16 @4096;
    //     xb [16][130][130][68] bf16 @1183744 (36.8 MB) -> total ~38 MB
    float*          cbias = (float*)d_ws;
    unsigned short* wfilt = (unsigned short*)((char*)d_ws + 4096);
    unsigned short* xb    = (unsigned short*)((char*)d_ws + 4096 + 1179648);

    k_pc<<<NTILES + BATCH * XBH, 256, 0, stream>>>(cond, sel_w, sel_b, filt_w, filt_b, x,
                                                   wfilt, cbias, xb);

    dim3 grid(WW / WT, HH / RT, BATCH);                  // 4 x 32 x 16 = 2048 blocks
    k_conv<<<grid, 256, 0, stream>>>(xb, wfilt, cbias, out);
}

// Round 7
// 173.773 us; speedup vs baseline: 1.0573x; 1.0573x over previous
//
#include <hip/hip_runtime.h>
#include <stdint.h>

#define BATCH 16
#define CIN   64
#define COUT  64
#define NBR   8
#define HH    128
#define WW    128
#define XBH   130              // padded height
#define XBW   130              // padded width
#define PSTR  68               // ushorts per pixel in xb AND in LDS (64 ch + 4 pad)
#define NTILES 1024

typedef __attribute__((ext_vector_type(8)))  short short8;
typedef __attribute__((ext_vector_type(16))) float f32x16;

// round-half-up f32->bf16 (inputs are tame normals; 3.4x error headroom measured)
__device__ __forceinline__ unsigned int f2bf_hi(float f) {
    union { float f; uint32_t u; } v; v.f = f;
    return (v.u + 0x8000u) >> 16;
}
// RNE version
__device__ __forceinline__ unsigned short f2bf(float f) {
    union { float f; uint32_t u; } v; v.f = f;
    uint32_t u = v.u;
    return (unsigned short)((u + 0x7FFFu + ((u >> 16) & 1u)) >> 16);
}
__device__ __forceinline__ short8 gld_frag(const unsigned short* p) {
    union { uint4 u; short8 s; } t;
    t.u = *(const uint4*)p;            // 16B aligned
    return t.s;
}
__device__ __forceinline__ short8 lds_frag(const unsigned short* p) {
    union { uint2 u[2]; short8 s; } t;
    t.u[0] = *(const uint2*)p;         // 8B aligned
    t.u[1] = *(const uint2*)(p + 4);
    return t.s;
}
// async global->LDS, 16B per lane; LDS dest is wave-uniform base + lane*16
__device__ __forceinline__ void gload_lds16(const unsigned short* g, unsigned short* l) {
    __builtin_amdgcn_global_load_lds(
        (const __attribute__((address_space(1))) unsigned int*)g,
        (__attribute__((address_space(3))) unsigned int*)l, 16, 0, 0);
}

// -------- kernel 1: fused {softmax+filter combine (blocks<1024)} | {x->xb cast} --------
// xb[b][h'][w'][68] bf16, 136 B/pixel; rows 0/129 and cols 0/129 are zero halo.
// Cast branch: one padded row per block, coalesced f32 reads -> LDS transpose ->
// contiguous 8B NHWC writes. Zero rows are pure memset blocks.
__global__ __launch_bounds__(256)
void k_pc(const float* __restrict__ cond,
          const float* __restrict__ sel_w,
          const float* __restrict__ sel_b,
          const float* __restrict__ filt_w,
          const float* __restrict__ filt_b,
          const float* __restrict__ x,
          unsigned short* __restrict__ wfilt,
          float* __restrict__ cbias,
          unsigned short* __restrict__ xb) {
    __shared__ __align__(16) char smem[NBR * 144 * 16 + 64];   // 18496 B, aliased per branch
    const int tid = threadIdx.x;

    if (blockIdx.x < NTILES) {
        // ---------------- prep branch (unchanged, verified) ----------------
        float4* lw4 = (float4*)smem;
        float*  lg  = (float*)(smem + NBR * 144 * 16);
        float*  lw  = (float*)lw4;
        const int blk = blockIdx.x;
        const int b = blk >> 6, o = blk & 63;

        const float4* src4 = (const float4*)filt_w;
        #pragma unroll
        for (int i = tid; i < NBR * 144; i += 256)
            lw4[i] = src4[((i / 144) * COUT + o) * 144 + (i % 144)];

        {
            const int lane = tid & 63, w = tid >> 6;
            const float c0 = cond[b * CIN + lane];
            #pragma unroll
            for (int k = 0; k < 2; ++k) {
                const int n = w + k * 4;
                float p = c0 * sel_w[n * CIN + lane];
                #pragma unroll
                for (int off = 32; off > 0; off >>= 1)
                    p += __shfl_down(p, off, 64);
                if (lane == 0) lg[n] = p + sel_b[n];
            }
        }
        __syncthreads();

        float w8[NBR];
        {
            float m = -1e30f;
            #pragma unroll
            for (int n = 0; n < NBR; ++n) m = fmaxf(m, lg[n]);
            float s = 0.f;
            #pragma unroll
            for (int n = 0; n < NBR; ++n) { w8[n] = __expf(lg[n] - m); s += w8[n]; }
            const float inv = 1.f / s;
            #pragma unroll
            for (int n = 0; n < NBR; ++n) w8[n] *= inv;
        }

        #pragma unroll
        for (int idx = tid; idx < 576; idx += 256) {
            const int t = idx >> 6, c = idx & 63;
            float acc = 0.f;
            #pragma unroll
            for (int n = 0; n < NBR; ++n)
                acc += w8[n] * lw[n * 576 + c * 9 + t];
            wfilt[(((long)(b * 9 + t) * COUT + o) << 6) + c] = f2bf(acc);
        }
        if (tid == 0) {
            float ab = 0.f;
            #pragma unroll
            for (int n = 0; n < NBR; ++n) ab += w8[n] * filt_b[n * COUT + o];
            cbias[b * COUT + o] = ab;
        }
    } else {
        // ---------------- cast branch ----------------
        const int id = blockIdx.x - NTILES;        // 0 .. 16*130-1
        const int hp = id % XBH;
        const int b  = id / XBH;
        unsigned short* dst = xb + (long)(b * XBH + hp) * XBW * PSTR;

        if (hp == 0 || hp == XBH - 1) {            // zero halo row: 8840 ushorts
            uint2 z; z.x = z.y = 0u;
            for (int t = tid; t < XBW * PSTR / 4; t += 256)   // 2210 8B stores
                *(uint2*)&dst[t * 4] = z;
            return;
        }
        const int h = hp - 1;

        // LDS transpose buffer lt[w][66] ushorts (stride 66: 4-way max on writes,
        // ~2-way on reads; 16896 B)
        unsigned short* lt = (unsigned short*)smem;

        // read phase: 2048 float4 tasks; lanes cover contiguous 512B per channel-row
        #pragma unroll
        for (int k = 0; k < 8; ++k) {
            const int u = tid + k * 256;
            const int c = u >> 5;                  // 0..63
            const int j = u & 31;                  // float4 index along w
            const float4 v = *(const float4*)(x + ((long)(b * CIN + c) * HH + h) * WW + j * 4);
            const int w = j * 4;
            lt[(w    ) * 66 + c] = (unsigned short)f2bf_hi(v.x);
            lt[(w + 1) * 66 + c] = (unsigned short)f2bf_hi(v.y);
            lt[(w + 2) * 66 + c] = (unsigned short)f2bf_hi(v.z);
            lt[(w + 3) * 66 + c] = (unsigned short)f2bf_hi(v.w);
        }
        __syncthreads();

        // write phase: 130 pixels x 8 chunks of 8 channels, contiguous 8B stores
        for (int t = tid; t < XBW * 8; t += 256) {
            const int wp = t >> 3, q = t & 7;
            uint2 u0, u1;
            u0.x = u0.y = u1.x = u1.y = 0u;
            if (wp > 0 && wp < XBW - 1) {
                const unsigned int* lp = (const unsigned int*)&lt[(wp - 1) * 66 + q * 8];
                u0.x = lp[0]; u0.y = lp[1]; u1.x = lp[2]; u1.y = lp[3];
            }
            unsigned short* dp = dst + wp * PSTR + q * 8;    // 8B aligned (136B pixels)
            *(uint2*)dp       = u0;
            *(uint2*)(dp + 4) = u1;
            if (q == 7) {                                    // zero the 8B pad
                uint2 z; z.x = z.y = 0u;
                *(uint2*)(dst + wp * PSTR + 64) = z;
            }
        }
    }
}

// -------- kernel 2: conv, RT=4 tiles, 27.7KB LDS, 5 blocks/CU --------
#define RT 4
#define WT 32
#define SLABW 34                      // WT + 2 halo
#define SLABR 6                       // RT + 2 halo
#define ROWUS (SLABW * PSTR)          // 2312 ushorts = 4624 B per slab row (16B multiple)
#define NCHUNK (SLABR * ROWUS / 8)    // 1734 16B chunks per slab

__global__ __launch_bounds__(256, 5)
void k_conv(const unsigned short* __restrict__ xb,
            const unsigned short* __restrict__ wfilt,
            const float* __restrict__ cbias,
            float* __restrict__ out) {
    __shared__ unsigned short lx[SLABR * ROWUS];          // 27744 B

    const int b  = blockIdx.z;
    const int h0 = blockIdx.y * RT;
    const int w0 = blockIdx.x * WT;
    const int tid = threadIdx.x;

    // ---- stage slab: 6 contiguous 4624B row segments, fire-and-forget DMA ----
    const unsigned short* srcb = xb + ((long)(b * XBH + h0) * XBW + w0) * PSTR;
    #pragma unroll
    for (int k = 0; k < 7; ++k) {
        const int t = tid + k * 256;
        if (t < NCHUNK) {
            const int row = t / 289;              // 289 chunks per row (4624/16)
            const int rc  = t - row * 289;
            gload_lds16(srcb + (long)row * (XBW * PSTR) + rc * 8, lx + t * 8);
        }
    }

    const int lane = tid & 63;
    const int wave = tid >> 6;
    const int l31  = lane & 31;
    const int lh   = lane >> 5;
    const int wp   = wave & 1;        // row-pair index (output rows 2wp, 2wp+1)
    const int wc   = wave >> 1;       // channel half (out channels wc*32..wc*32+31)
    const int r0   = wp * 2;

    // A source for this wave's channel half
    const unsigned short* wf = wfilt + (long)b * 9 * COUT * CIN + wc * 32 * CIN;

    // prefetch tap-0 A fragments (overlaps the LDS DMA)
    short8 A[4];
    #pragma unroll
    for (int cc = 0; cc < 4; ++cc)
        A[cc] = gld_frag(wf + l31 * CIN + cc * 16 + lh * 8);

    // bias-initialized accumulators (C/D row m = (i&3)+8*(i>>2)+4*lh)
    f32x16 acc0, acc1;
    #pragma unroll
    for (int i = 0; i < 16; ++i) {
        const int m = (i & 3) + 8 * (i >> 2) + 4 * lh;
        const float bb = cbias[b * COUT + wc * 32 + m];
        acc0[i] = bb; acc1[i] = bb;
    }

    __syncthreads();   // vmcnt(0) drain: slab + A frags ready

    #pragma unroll
    for (int tap = 0; tap < 9; ++tap) {
        // prefetch next tap's A into fresh registers BEFORE this tap's MFMAs
        short8 nA[4];
        if (tap < 8) {
            const unsigned short* wn = wf + (long)(tap + 1) * COUT * CIN;
            #pragma unroll
            for (int cc = 0; cc < 4; ++cc)
                nA[cc] = gld_frag(wn + l31 * CIN + cc * 16 + lh * 8);
        }
        const int kh = tap / 3, kw = tap % 3;
        #pragma unroll
        for (int cc = 0; cc < 4; ++cc) {
            const int kofs = cc * 16 + lh * 8;
            short8 b0 = lds_frag(&lx[((r0     + kh) * SLABW + l31 + kw) * PSTR + kofs]);
            short8 b1 = lds_frag(&lx[((r0 + 1 + kh) * SLABW + l31 + kw) * PSTR + kofs]);
            acc0 = __builtin_amdgcn_mfma_f32_32x32x16_bf16(A[cc], b0, acc0, 0, 0, 0);
            acc1 = __builtin_amdgcn_mfma_f32_32x32x16_bf16(A[cc], b1, acc1, 0, 0, 0);
        }
        #pragma unroll
        for (int cc = 0; cc < 4; ++cc) A[cc] = nA[cc];
    }

    #pragma unroll
    for (int pb = 0; pb < 2; ++pb) {
        const f32x16 v = pb == 0 ? acc0 : acc1;
        const int hrow = h0 + r0 + pb;
        float* op = out + (((long)(b * COUT + wc * 32) * HH + hrow) * WW + w0 + l31);
        #pragma unroll
        for (int i = 0; i < 16; ++i) {
            const int m = (i & 3) + 8 * (i >> 2) + 4 * lh;
            op[(long)m * HH * WW] = v[i];
        }
    }
}

extern "C" void kernel_launch(void* const* d_in, const int* in_sizes, int n_in,
                              void* d_out, int out_size, void* d_ws, size_t ws_size,
                              hipStream_t stream) {
    const float* x      = (const float*)d_in[0];
    const float* cond   = (const float*)d_in[1];
    const float* filt_w = (const float*)d_in[2];
    const float* filt_b = (const float*)d_in[3];
    const float* sel_w  = (const float*)d_in[4];
    const float* sel_b  = (const float*)d_in[5];
    float* out = (float*)d_out;

    // ws: cbias [16][64] f32 @0; wfilt [16][9][64][64] bf16 @4096;
    //     xb [16][130][130][68] bf16 @1183744 (36.8 MB) -> total ~38 MB
    float*          cbias = (float*)d_ws;
    unsigned short* wfilt = (unsigned short*)((char*)d_ws + 4096);
    unsigned short* xb    = (unsigned short*)((char*)d_ws + 4096 + 1179648);

    k_pc<<<NTILES + BATCH * XBH, 256, 0, stream>>>(cond, sel_w, sel_b, filt_w, filt_b, x,
                                                   wfilt, cbias, xb);

    dim3 grid(WW / WT, HH / RT, BATCH);                  // 4 x 32 x 16 = 2048 blocks
    k_conv<<<grid, 256, 0, stream>>>(xb, wfilt, cbias, out);
}

// Round 9
// 163.457 us; speedup vs baseline: 1.1240x; 1.0631x over previous
//
#include <hip/hip_runtime.h>
#include <stdint.h>

#define BATCH 16
#define CIN   64
#define COUT  64
#define NBR   8
#define HH    128
#define WW    128
#define XBH   130              // padded height
#define XBW   130              // padded width
#define PSTR  68               // ushorts per pixel in xb AND in LDS (64 ch + 4 pad)
#define NTILES 1024

typedef __attribute__((ext_vector_type(8)))  short short8;
typedef __attribute__((ext_vector_type(16))) float f32x16;

// round-half-up f32->bf16 (inputs are tame normals; 3.4x error headroom measured)
__device__ __forceinline__ unsigned int f2bf_hi(float f) {
    union { float f; uint32_t u; } v; v.f = f;
    return (v.u + 0x8000u) >> 16;
}
// RNE version
__device__ __forceinline__ unsigned short f2bf(float f) {
    union { float f; uint32_t u; } v; v.f = f;
    uint32_t u = v.u;
    return (unsigned short)((u + 0x7FFFu + ((u >> 16) & 1u)) >> 16);
}
__device__ __forceinline__ short8 gld_frag(const unsigned short* p) {
    union { uint4 u; short8 s; } t;
    t.u = *(const uint4*)p;            // 16B aligned
    return t.s;
}
__device__ __forceinline__ short8 lds_frag(const unsigned short* p) {
    union { uint2 u[2]; short8 s; } t;
    t.u[0] = *(const uint2*)p;         // 8B aligned
    t.u[1] = *(const uint2*)(p + 4);
    return t.s;
}
// async global->LDS, 16B per lane; LDS dest is wave-uniform base + lane*16
__device__ __forceinline__ void gload_lds16(const unsigned short* g, unsigned short* l) {
    __builtin_amdgcn_global_load_lds(
        (const __attribute__((address_space(1))) unsigned int*)g,
        (__attribute__((address_space(3))) unsigned int*)l, 16, 0, 0);
}

// counted-wait phase boundary: drain all but N newest VMEM, then raw barrier.
// sched_barrier(0) fences both the wait (rule 18) and the barrier.
#define WAITP(N) do {                                              \
    asm volatile("s_waitcnt vmcnt(" #N ")" ::: "memory");          \
    __builtin_amdgcn_sched_barrier(0);                             \
    __builtin_amdgcn_s_barrier();                                  \
    __builtin_amdgcn_sched_barrier(0);                             \
} while (0)

// -------- kernel 1: fused {softmax+filter combine (blocks<1024)} | {x->xb cast} --------
// xb[b][h'][w'][68] bf16, 136 B/pixel; rows 0/129 and cols 0/129 are zero halo.
// Cast branch: one padded row per block, coalesced f32 reads -> LDS transpose ->
// contiguous 8B NHWC writes. Zero rows are pure memset blocks.
__global__ __launch_bounds__(256)
void k_pc(const float* __restrict__ cond,
          const float* __restrict__ sel_w,
          const float* __restrict__ sel_b,
          const float* __restrict__ filt_w,
          const float* __restrict__ filt_b,
          const float* __restrict__ x,
          unsigned short* __restrict__ wfilt,
          float* __restrict__ cbias,
          unsigned short* __restrict__ xb) {
    __shared__ __align__(16) char smem[NBR * 144 * 16 + 64];   // 18496 B, aliased per branch
    const int tid = threadIdx.x;

    if (blockIdx.x < NTILES) {
        // ---------------- prep branch (unchanged, verified) ----------------
        float4* lw4 = (float4*)smem;
        float*  lg  = (float*)(smem + NBR * 144 * 16);
        float*  lw  = (float*)lw4;
        const int blk = blockIdx.x;
        const int b = blk >> 6, o = blk & 63;

        const float4* src4 = (const float4*)filt_w;
        #pragma unroll
        for (int i = tid; i < NBR * 144; i += 256)
            lw4[i] = src4[((i / 144) * COUT + o) * 144 + (i % 144)];

        {
            const int lane = tid & 63, w = tid >> 6;
            const float c0 = cond[b * CIN + lane];
            #pragma unroll
            for (int k = 0; k < 2; ++k) {
                const int n = w + k * 4;
                float p = c0 * sel_w[n * CIN + lane];
                #pragma unroll
                for (int off = 32; off > 0; off >>= 1)
                    p += __shfl_down(p, off, 64);
                if (lane == 0) lg[n] = p + sel_b[n];
            }
        }
        __syncthreads();

        float w8[NBR];
        {
            float m = -1e30f;
            #pragma unroll
            for (int n = 0; n < NBR; ++n) m = fmaxf(m, lg[n]);
            float s = 0.f;
            #pragma unroll
            for (int n = 0; n < NBR; ++n) { w8[n] = __expf(lg[n] - m); s += w8[n]; }
            const float inv = 1.f / s;
            #pragma unroll
            for (int n = 0; n < NBR; ++n) w8[n] *= inv;
        }

        #pragma unroll
        for (int idx = tid; idx < 576; idx += 256) {
            const int t = idx >> 6, c = idx & 63;
            float acc = 0.f;
            #pragma unroll
            for (int n = 0; n < NBR; ++n)
                acc += w8[n] * lw[n * 576 + c * 9 + t];
            wfilt[(((long)(b * 9 + t) * COUT + o) << 6) + c] = f2bf(acc);
        }
        if (tid == 0) {
            float ab = 0.f;
            #pragma unroll
            for (int n = 0; n < NBR; ++n) ab += w8[n] * filt_b[n * COUT + o];
            cbias[b * COUT + o] = ab;
        }
    } else {
        // ---------------- cast branch ----------------
        const int id = blockIdx.x - NTILES;        // 0 .. 16*130-1
        const int hp = id % XBH;
        const int b  = id / XBH;
        unsigned short* dst = xb + (long)(b * XBH + hp) * XBW * PSTR;

        if (hp == 0 || hp == XBH - 1) {            // zero halo row: 8840 ushorts
            uint2 z; z.x = z.y = 0u;
            for (int t = tid; t < XBW * PSTR / 4; t += 256)   // 2210 8B stores
                *(uint2*)&dst[t * 4] = z;
            return;
        }
        const int h = hp - 1;

        // LDS transpose buffer lt[w][66] ushorts
        unsigned short* lt = (unsigned short*)smem;

        // read phase: 2048 float4 tasks; lanes cover contiguous 512B per channel-row
        #pragma unroll
        for (int k = 0; k < 8; ++k) {
            const int u = tid + k * 256;
            const int c = u >> 5;                  // 0..63
            const int j = u & 31;                  // float4 index along w
            const float4 v = *(const float4*)(x + ((long)(b * CIN + c) * HH + h) * WW + j * 4);
            const int w = j * 4;
            lt[(w    ) * 66 + c] = (unsigned short)f2bf_hi(v.x);
            lt[(w + 1) * 66 + c] = (unsigned short)f2bf_hi(v.y);
            lt[(w + 2) * 66 + c] = (unsigned short)f2bf_hi(v.z);
            lt[(w + 3) * 66 + c] = (unsigned short)f2bf_hi(v.w);
        }
        __syncthreads();

        // write phase: 130 pixels x 8 chunks of 8 channels, contiguous 8B stores
        for (int t = tid; t < XBW * 8; t += 256) {
            const int wp = t >> 3, q = t & 7;
            uint2 u0, u1;
            u0.x = u0.y = u1.x = u1.y = 0u;
            if (wp > 0 && wp < XBW - 1) {
                const unsigned int* lp = (const unsigned int*)&lt[(wp - 1) * 66 + q * 8];
                u0.x = lp[0]; u0.y = lp[1]; u1.x = lp[2]; u1.y = lp[3];
            }
            unsigned short* dp = dst + wp * PSTR + q * 8;    // 8B aligned (136B pixels)
            *(uint2*)dp       = u0;
            *(uint2*)(dp + 4) = u1;
            if (q == 7) {                                    // zero the 8B pad
                uint2 z; z.x = z.y = 0u;
                *(uint2*)(dst + wp * PSTR + 64) = z;
            }
        }
    }
}

// -------- kernel 2: conv, RT=4, 27.7KB LDS, 4 blocks/CU, 3-phase counted-vmcnt overlap ----
#define RT 4
#define WT 32
#define SLABW 34                      // WT + 2 halo
#define SLABR 6                       // RT + 2 halo
#define ROWUS (SLABW * PSTR)          // 2312 ushorts = 4624 B per slab row (16B multiple)
#define NCHUNK (SLABR * ROWUS / 8)    // 1734 16B chunks per slab

// DMA rounds are chunk-ordered => row-major: rounds 0-4 cover rows 0-3 (chunks<1280>=1155),
// round 5 covers row 4 (ends 1444<1536), round 6 covers rest of row 5.
// Tap row kh reads slab rows kh..kh+3 => phase waits: vmcnt(2) / vmcnt(5) / vmcnt(4)
// (counts safe: >=N younger VMEM ops always separate the needed round from the window).
__global__ __launch_bounds__(256, 4)
void k_conv(const unsigned short* __restrict__ xb,
            const unsigned short* __restrict__ wfilt,
            const float* __restrict__ cbias,
            float* __restrict__ out) {
    __shared__ unsigned short lx[SLABR * ROWUS];          // 27744 B

    const int b  = blockIdx.z;
    const int h0 = blockIdx.y * RT;
    const int w0 = blockIdx.x * WT;
    const int tid = threadIdx.x;

    const int lane = tid & 63;
    const int wave = tid >> 6;
    const int l31  = lane & 31;
    const int lh   = lane >> 5;
    const int wp   = wave & 1;        // row-pair index (output rows 2wp, 2wp+1)
    const int wc   = wave >> 1;       // channel half (out channels wc*32..wc*32+31)
    const int r0   = wp * 2;

    // A source for this wave's channel half; tap-0 A prefetch FIRST (oldest VMEM)
    const unsigned short* wf = wfilt + (long)b * 9 * COUT * CIN + wc * 32 * CIN;
    short8 A[4];
    #pragma unroll
    for (int cc = 0; cc < 4; ++cc)
        A[cc] = gld_frag(wf + l31 * CIN + cc * 16 + lh * 8);

    // ---- stage slab: 7 DMA rounds in chunk (row-major) order ----
    const unsigned short* srcb = xb + ((long)(b * XBH + h0) * XBW + w0) * PSTR;
    #pragma unroll
    for (int k = 0; k < 7; ++k) {
        const int t = tid + k * 256;
        if (t < NCHUNK) {
            const int row = t / 289;              // 289 chunks per row (4624/16)
            const int rc  = t - row * 289;
            gload_lds16(srcb + (long)row * (XBW * PSTR) + rc * 8, lx + t * 8);
        }
    }

    // zero accumulators; bias added in epilogue (keeps staging window load-free)
    f32x16 acc0, acc1;
    #pragma unroll
    for (int i = 0; i < 16; ++i) { acc0[i] = 0.f; acc1[i] = 0.f; }

    #pragma unroll
    for (int tap = 0; tap < 9; ++tap) {
        if (tap == 0) WAITP(2);       // rows 0-3 ready; rounds 5,6 in flight
        if (tap == 3) WAITP(5);       // + row 4 ready; round 6 + nA in flight
        if (tap == 6) WAITP(4);       // + row 5 ready; nA in flight
        // prefetch next tap's A into fresh registers BEFORE this tap's MFMAs
        short8 nA[4];
        if (tap < 8) {
            const unsigned short* wn = wf + (long)(tap + 1) * COUT * CIN;
            #pragma unroll
            for (int cc = 0; cc < 4; ++cc)
                nA[cc] = gld_frag(wn + l31 * CIN + cc * 16 + lh * 8);
        }
        const int kh = tap / 3, kw = tap % 3;
        #pragma unroll
        for (int cc = 0; cc < 4; ++cc) {
            const int kofs = cc * 16 + lh * 8;
            short8 b0 = lds_frag(&lx[((r0     + kh) * SLABW + l31 + kw) * PSTR + kofs]);
            short8 b1 = lds_frag(&lx[((r0 + 1 + kh) * SLABW + l31 + kw) * PSTR + kofs]);
            acc0 = __builtin_amdgcn_mfma_f32_32x32x16_bf16(A[cc], b0, acc0, 0, 0, 0);
            acc1 = __builtin_amdgcn_mfma_f32_32x32x16_bf16(A[cc], b1, acc1, 0, 0, 0);
        }
        #pragma unroll
        for (int cc = 0; cc < 4; ++cc) A[cc] = nA[cc];
    }

    #pragma unroll
    for (int pb = 0; pb < 2; ++pb) {
        const f32x16 v = pb == 0 ? acc0 : acc1;
        const int hrow = h0 + r0 + pb;
        float* op = out + (((long)(b * COUT + wc * 32) * HH + hrow) * WW + w0 + l31);
        #pragma unroll
        for (int i = 0; i < 16; ++i) {
            const int m = (i & 3) + 8 * (i >> 2) + 4 * lh;
            op[(long)m * HH * WW] = v[i] + cbias[b * COUT + wc * 32 + m];
        }
    }
}

extern "C" void kernel_launch(void* const* d_in, const int* in_sizes, int n_in,
                              void* d_out, int out_size, void* d_ws, size_t ws_size,
                              hipStream_t stream) {
    const float* x      = (const float*)d_in[0];
    const float* cond   = (const float*)d_in[1];
    const float* filt_w = (const float*)d_in[2];
    const float* filt_b = (const float*)d_in[3];
    const float* sel_w  = (const float*)d_in[4];
    const float* sel_b  = (const float*)d_in[5];
    float* out = (float*)d_out;

    // ws: cbias [16][64] f32 @0; wfilt [16][9][64][64] bf16 @4096;
    //     xb [16][130][130][68] bf16 @1183744 (36.8 MB) -> total ~38 MB
    float*          cbias = (float*)d_ws;
    unsigned short* wfilt = (unsigned short*)((char*)d_ws + 4096);
    unsigned short* xb    = (unsigned short*)((char*)d_ws + 4096 + 1179648);

    k_pc<<<NTILES + BATCH * XBH, 256, 0, stream>>>(cond, sel_w, sel_b, filt_w, filt_b, x,
                                                   wfilt, cbias, xb);

    dim3 grid(WW / WT, HH / RT, BATCH);                  // 4 x 32 x 16 = 2048 blocks
    k_conv<<<grid, 256, 0, stream>>>(xb, wfilt, cbias, out);
}